// Round 2
// baseline (378.718 us; speedup 1.0000x reference)
//
#include <hip/hip_runtime.h>

// ---- problem constants (from reference) ----
#define N_NODES   100000
#define T_TYPES   4
#define E_EDGES   400000
#define E4        100000                    // int4 groups per type-array
#define G_TOT     400000                    // total int4 groups = TE_TOT/4
#define C_CH      2
#define W_INF     128
#define DD        64
#define NUM_CLASS 16
#define BETA      0.5f
#define M_TGT     10000

// counting-sort CSR (padded per 64-row sub-bucket, exact per-row offsets)
#define NSB       1563                      // ceil(100000/64) sub-buckets
#define SBPAD     1408                      // slots/sub-bucket (mean 1024, sd 32 -> +12 sigma)
#define NCNT      100032                    // rowcnt array size (64-padded)
#define CHUNK_G   1024                      // int4 groups per edge block (4096 edges)
#define NPART_BLK 391                       // ceil(400000/1024)
#define PROJ_BLK  1563                      // ceil(100000/64)

// bf16 planes: u32 at [n*64 + d] = bf16(ch0) | bf16(ch1)<<16
static const size_t PLANE2 = (size_t)N_NODES * DD;    // u32 elements per plane

typedef __attribute__((ext_vector_type(8))) short short8x;   // 8 bf16 (4 VGPRs)
typedef __attribute__((ext_vector_type(4))) float f32x4;     // MFMA C/D

__device__ __forceinline__ unsigned bf16rne(float x) {   // RNE f32 -> bf16 bits
    unsigned u = __float_as_uint(x);
    return (u + 0x7FFFu + ((u >> 16) & 1u)) >> 16;
}
__device__ __forceinline__ unsigned packbf(float a, float b) {
    return bf16rne(a) | (bf16rne(b) << 16);
}
__device__ __forceinline__ float bflo(unsigned u) { return __uint_as_float(u << 16); }
__device__ __forceinline__ float bfhi(unsigned u) { return __uint_as_float(u & 0xFFFF0000u); }

__device__ __forceinline__ void load_filter(const float* cw, int layer,
                                            float* f0, float* f1) {
    float m0 = -1e30f, m1 = -1e30f;
    #pragma unroll
    for (int t = 0; t < T_TYPES; ++t) {
        f0[t] = cw[layer * C_CH * T_TYPES + t];
        f1[t] = cw[layer * C_CH * T_TYPES + T_TYPES + t];
        m0 = fmaxf(m0, f0[t]); m1 = fmaxf(m1, f1[t]);
    }
    float s0 = 0.f, s1 = 0.f;
    #pragma unroll
    for (int t = 0; t < T_TYPES; ++t) {
        f0[t] = __expf(f0[t] - m0); s0 += f0[t];
        f1[t] = __expf(f1[t] - m1); s1 += f1[t];
    }
    #pragma unroll
    for (int t = 0; t < T_TYPES; ++t) { f0[t] /= s0; f1[t] /= s1; }
}

// ---------------------------------------------------------------------------
// prep: Wsb[c][d][k] = bf16(Ws[c][k][d]) (blocks 0..63) + rowcnt zero (64..454)
// ---------------------------------------------------------------------------
__global__ void prep_kernel(const float* __restrict__ Ws,
                            unsigned short* __restrict__ Wsb,
                            int* __restrict__ rowcnt) {
    int b = blockIdx.x;
    int tid = threadIdx.x;
    if (b < 64) {
        int idx = b * 256 + tid;
        int c   = idx >> 13;
        int rem = idx & 8191;
        int d   = rem >> 7;
        int k   = rem & 127;
        Wsb[idx] = (unsigned short)bf16rne(Ws[c * (W_INF * DD) + k * DD + d]);
    } else {
        int idx = (b - 64) * 256 + tid;
        if (idx < NCNT) rowcnt[idx] = 0;
    }
}

// ---------------------------------------------------------------------------
// Fused: blocks [0, NPART_BLK) count edges per destination row (low-contention
// global atomics over 100k addresses, reads only the rows arrays).
// Blocks [NPART_BLK, +PROJ_BLK) run the LDS-free MFMA projection.
// ---------------------------------------------------------------------------
__global__ __launch_bounds__(256) void count_proj_kernel(
        const int* __restrict__ edge_index,
        int* __restrict__ rowcnt,
        const float* __restrict__ X,
        const unsigned short* __restrict__ Wsb,
        unsigned* __restrict__ Xp16) {
    int tid = threadIdx.x;

    if (blockIdx.x < NPART_BLK) {
        // ---------------- per-row count ----------------
        int p = blockIdx.x;
        #pragma unroll
        for (int g = 0; g < 4; ++g) {
            int idx = p * CHUNK_G + g * 256 + tid;
            if (idx < G_TOT) {
                int t = idx / E4, r = idx - t * E4;
                const int4* rp = (const int4*)(edge_index + (size_t)t * 2 * E_EDGES);
                int4 rw = rp[r];
                atomicAdd(&rowcnt[rw.x], 1);
                atomicAdd(&rowcnt[rw.y], 1);
                atomicAdd(&rowcnt[rw.z], 1);
                atomicAdd(&rowcnt[rw.w], 1);
            }
        }
    } else {
        // ---------------- MFMA projection (LDS-free) ----------------
        int row0 = (blockIdx.x - NPART_BLK) * 64;
        int wave = tid >> 6, lane = tid & 63;
        int m = lane & 15, q = lane >> 4;
        int arow = row0 + wave * 16 + m;
        const float4* X4 = (const float4*)X;
        union { short8x s; uint4 u; } A[4];
        bool valid = arow < N_NODES;
        #pragma unroll
        for (int ks = 0; ks < 4; ++ks) {
            float4 va = make_float4(0.f, 0.f, 0.f, 0.f), vb = va;
            if (valid) {
                va = X4[(size_t)arow * 32 + ks * 8 + q * 2];
                vb = X4[(size_t)arow * 32 + ks * 8 + q * 2 + 1];
            }
            A[ks].u = make_uint4(packbf(va.x, va.y), packbf(va.z, va.w),
                                 packbf(vb.x, vb.y), packbf(vb.z, vb.w));
        }

        #pragma unroll
        for (int ct = 0; ct < 4; ++ct) {
            f32x4 acc0 = {0.f, 0.f, 0.f, 0.f};
            f32x4 acc1 = {0.f, 0.f, 0.f, 0.f};
            #pragma unroll
            for (int ks = 0; ks < 4; ++ks) {
                short8x B0 = *(const short8x*)(Wsb + (ct * 16 + m) * 128 + ks * 32 + q * 8);
                short8x B1 = *(const short8x*)(Wsb + 8192 + (ct * 16 + m) * 128 + ks * 32 + q * 8);
                acc0 = __builtin_amdgcn_mfma_f32_16x16x32_bf16(A[ks].s, B0, acc0, 0, 0, 0);
                acc1 = __builtin_amdgcn_mfma_f32_16x16x32_bf16(A[ks].s, B1, acc1, 0, 0, 0);
            }
            #pragma unroll
            for (int r = 0; r < 4; ++r) {
                int row = row0 + wave * 16 + q * 4 + r;
                if (row < N_NODES)
                    Xp16[(size_t)row * DD + ct * 16 + m] = packbf(acc0[r], acc1[r]);
            }
        }
    }
}

// ---------------------------------------------------------------------------
// Per-sub-bucket exclusive scan: one lane per row, one wave per 64-row bucket.
// rowcnt[row] becomes the exact start cursor (in place); offs[row] = end.
// ---------------------------------------------------------------------------
__global__ __launch_bounds__(256) void scan_kernel(int* __restrict__ rowcnt,
                                                   int* __restrict__ offs) {
    int sb   = blockIdx.x * 4 + (threadIdx.x >> 6);
    int lane = threadIdx.x & 63;
    if (sb >= NSB) return;
    int row = sb * 64 + lane;
    int c = (row < N_NODES) ? rowcnt[row] : 0;
    int inc = c;
    #pragma unroll
    for (int off = 1; off < 64; off <<= 1) {
        int v = __shfl_up(inc, off);
        if (lane >= off) inc += v;
    }
    int start = sb * SBPAD + inc - c;
    if (row < N_NODES) {
        rowcnt[row] = start;            // becomes scatter cursor
        offs[row]   = start + c;        // end offset for gather/tail
    }
}

// ---------------------------------------------------------------------------
// Scatter: re-read edges, place each record at its exact row-sorted slot.
// No LDS, no barriers -> fully latency-hidden streaming.
// record: edata2[slot] = { col | t<<17 , packbf(val*f0_l1[t], val*f1_l1[t]) }
// ---------------------------------------------------------------------------
__global__ __launch_bounds__(256) void scatter_kernel(
        const int* __restrict__ edge_index,
        const float* __restrict__ edge_value,
        const float* __restrict__ cw,
        int* __restrict__ rowcur,
        int2* __restrict__ edata2) {
    int tid = threadIdx.x;
    int p = blockIdx.x;
    float f0[T_TYPES], f1[T_TYPES];
    load_filter(cw, 0, f0, f1);

    #pragma unroll
    for (int g = 0; g < 4; ++g) {
        int idx = p * CHUNK_G + g * 256 + tid;
        if (idx < G_TOT) {
            int t = idx / E4, r = idx - t * E4;
            const int* bptr = edge_index + (size_t)t * 2 * E_EDGES;
            int4   rw = ((const int4*)bptr)[r];
            int4   cl = ((const int4*)(bptr + E_EDGES))[r];
            float4 vv = ((const float4*)(edge_value + (size_t)t * E_EDGES))[r];
            int tb = t << 17;
            unsigned wp = 0;  // per-type packed weights share f0[t],f1[t]
            int   rr[4] = {rw.x, rw.y, rw.z, rw.w};
            int   cc[4] = {cl.x, cl.y, cl.z, cl.w};
            float vf[4] = {vv.x, vv.y, vv.z, vv.w};
            (void)wp;
            #pragma unroll
            for (int k = 0; k < 4; ++k) {
                int slot = atomicAdd(&rowcur[rr[k]], 1);
                edata2[slot] = make_int2(cc[k] | tb,
                                         (int)packbf(vf[k] * f0[t], vf[k] * f1[t]));
            }
        }
    }
}

// ---------------------------------------------------------------------------
// Quarter-wave bf16 gather helpers: s16 = lane&15 covers d = {4s..4s+3} both
// channels as uint4 = 16 B/lane; sub = lane>>4 interleaves 4 edges per wave.
// ---------------------------------------------------------------------------
__device__ __forceinline__ void qfma(const uint4 h, unsigned wp,
                                     float4& a, float4& b) {
    float w0 = bflo(wp), w1 = bfhi(wp);
    a.x = fmaf(w0, bflo(h.x), a.x);
    a.y = fmaf(w1, bfhi(h.x), a.y);
    a.z = fmaf(w0, bflo(h.y), a.z);
    a.w = fmaf(w1, bfhi(h.y), a.w);
    b.x = fmaf(w0, bflo(h.z), b.x);
    b.y = fmaf(w1, bfhi(h.z), b.y);
    b.z = fmaf(w0, bflo(h.w), b.z);
    b.w = fmaf(w1, bfhi(h.w), b.w);
}

__device__ __forceinline__ void qreduce(float4& a, float4& b) {
    a.x += __shfl_xor(a.x, 16); a.y += __shfl_xor(a.y, 16);
    a.z += __shfl_xor(a.z, 16); a.w += __shfl_xor(a.w, 16);
    b.x += __shfl_xor(b.x, 16); b.y += __shfl_xor(b.y, 16);
    b.z += __shfl_xor(b.z, 16); b.w += __shfl_xor(b.w, 16);
    a.x += __shfl_xor(a.x, 32); a.y += __shfl_xor(a.y, 32);
    a.z += __shfl_xor(a.z, 32); a.w += __shfl_xor(a.w, 32);
    b.x += __shfl_xor(b.x, 32); b.y += __shfl_xor(b.y, 32);
    b.z += __shfl_xor(b.z, 32); b.w += __shfl_xor(b.w, 32);
}

__device__ __forceinline__ int row_beg(const int* offs, int row) {
    return ((row & 63) == 0) ? (row >> 6) * SBPAD : offs[row - 1];
}

// Layer 1: all N rows; bf16 in (Xp16), bf16 out (H116). One wave per row.
__global__ __launch_bounds__(256) void spmm_gather(const unsigned* __restrict__ Hin16,
                                                   unsigned* __restrict__ Hout16,
                                                   const int* __restrict__ offs,
                                                   const int2* __restrict__ edata2) {
    int lane = threadIdx.x & 63;
    int s16 = lane & 15, sub = lane >> 4;
    int row  = (blockIdx.x * blockDim.x + threadIdx.x) >> 6;
    int beg = row_beg(offs, row);
    int end = offs[row];
    const uint4* hp = (const uint4*)Hin16;
    float4 a = make_float4(0.f, 0.f, 0.f, 0.f);
    float4 b = make_float4(0.f, 0.f, 0.f, 0.f);
    int i = beg + sub;
    for (; i + 4 < end; i += 8) {                 // 2 edges per quarter per iter
        int2 e0 = edata2[i];
        int2 e1 = edata2[i + 4];
        uint4 h0 = hp[(size_t)(e0.x & 0x1FFFF) * 16 + s16];
        uint4 h1 = hp[(size_t)(e1.x & 0x1FFFF) * 16 + s16];
        qfma(h0, (unsigned)e0.y, a, b);
        qfma(h1, (unsigned)e1.y, a, b);
    }
    if (i < end) {
        int2 e = edata2[i];
        uint4 h = hp[(size_t)(e.x & 0x1FFFF) * 16 + s16];
        qfma(h, (unsigned)e.y, a, b);
    }
    qreduce(a, b);
    if (sub == 0)
        ((uint4*)Hout16)[(size_t)row * 16 + s16] =
            make_uint4(packbf(a.x, a.y), packbf(a.z, a.w),
                       packbf(b.x, b.y), packbf(b.z, b.w));
}

// ---------------------------------------------------------------------------
// Fused layer-2 gather (target rows) + tail MLP. Block = 4 waves = 4 targets.
// Layer-2 edge weights = stored_l1_weight * (f_l2[t]/f_l1[t]).
// ---------------------------------------------------------------------------
__global__ __launch_bounds__(256) void tgt_tail_kernel(const unsigned* __restrict__ Hin16,
                                                       const unsigned* __restrict__ Xp16,
                                                       const int* __restrict__ offs,
                                                       const int2* __restrict__ edata2,
                                                       const float* __restrict__ cw,
                                                       const int* __restrict__ tgt,
                                                       const float* __restrict__ lin1_w,
                                                       const float* __restrict__ lin1_b,
                                                       const float* __restrict__ lin_w,
                                                       const float* __restrict__ lin_b,
                                                       float* __restrict__ out) {
    __shared__ float l1w[W_INF * DD];        // 32 KB
    __shared__ float lw[DD * NUM_CLASS];     // 4 KB
    __shared__ float l1b[DD];
    __shared__ float lb[NUM_CLASS];
    __shared__ float hc[4][W_INF];
    __shared__ float hmid[4][DD];

    int tid = threadIdx.x;
    {
        const float4* g = (const float4*)lin1_w;
        float4* s = (float4*)l1w;
        #pragma unroll
        for (int i = 0; i < 8; ++i) s[tid + 256 * i] = g[tid + 256 * i];
        ((float4*)lw)[tid] = ((const float4*)lin_w)[tid];
        if (tid < DD) l1b[tid] = lin1_b[tid];
        else if (tid < DD + NUM_CLASS) lb[tid - DD] = lin_b[tid - DD];
    }

    float f0a[T_TYPES], f1a[T_TYPES], f0b[T_TYPES], f1b[T_TYPES];
    load_filter(cw, 0, f0a, f1a);
    load_filter(cw, 1, f0b, f1b);
    float r0[T_TYPES], r1[T_TYPES];
    #pragma unroll
    for (int t = 0; t < T_TYPES; ++t) { r0[t] = f0b[t] / f0a[t]; r1[t] = f1b[t] / f1a[t]; }

    int w = tid >> 6, lane = tid & 63;
    int s16 = lane & 15, sub = lane >> 4;
    int m = blockIdx.x * 4 + w;               // M = 10000 = 2500*4
    int row = tgt[m];
    int beg = row_beg(offs, row);
    int end = offs[row];
    const uint4* hp = (const uint4*)Hin16;
    float4 a = make_float4(0.f, 0.f, 0.f, 0.f);
    float4 b = make_float4(0.f, 0.f, 0.f, 0.f);
    for (int i = beg + sub; i < end; i += 4) {
        int2 e = edata2[i];
        int t = (e.x >> 17) & 3;
        uint4 h = hp[(size_t)(e.x & 0x1FFFF) * 16 + s16];
        unsigned wp = (unsigned)e.y;
        float w0 = bflo(wp) * r0[t], w1 = bfhi(wp) * r1[t];
        a.x = fmaf(w0, bflo(h.x), a.x);
        a.y = fmaf(w1, bfhi(h.x), a.y);
        a.z = fmaf(w0, bflo(h.y), a.z);
        a.w = fmaf(w1, bfhi(h.y), a.w);
        b.x = fmaf(w0, bflo(h.z), b.x);
        b.y = fmaf(w1, bfhi(h.z), b.y);
        b.z = fmaf(w0, bflo(h.w), b.z);
        b.w = fmaf(w1, bfhi(h.w), b.w);
    }
    qreduce(a, b);

    if (sub == 0) {
        uint4 xu = ((const uint4*)Xp16)[(size_t)row * 16 + s16];
        int d0 = 4 * s16;
        hc[w][d0 + 0]      = fmaxf(BETA * bflo(xu.x) + (1.f - BETA) * a.x, 0.f);
        hc[w][DD + d0 + 0] = fmaxf(BETA * bfhi(xu.x) + (1.f - BETA) * a.y, 0.f);
        hc[w][d0 + 1]      = fmaxf(BETA * bflo(xu.y) + (1.f - BETA) * a.z, 0.f);
        hc[w][DD + d0 + 1] = fmaxf(BETA * bfhi(xu.y) + (1.f - BETA) * a.w, 0.f);
        hc[w][d0 + 2]      = fmaxf(BETA * bflo(xu.z) + (1.f - BETA) * b.x, 0.f);
        hc[w][DD + d0 + 2] = fmaxf(BETA * bfhi(xu.z) + (1.f - BETA) * b.y, 0.f);
        hc[w][d0 + 3]      = fmaxf(BETA * bflo(xu.w) + (1.f - BETA) * b.z, 0.f);
        hc[w][DD + d0 + 3] = fmaxf(BETA * bfhi(xu.w) + (1.f - BETA) * b.w, 0.f);
    }
    __syncthreads();

    float a1 = l1b[lane];
    #pragma unroll 8
    for (int k = 0; k < W_INF; ++k)
        a1 = fmaf(hc[w][k], l1w[k * DD + lane], a1);
    hmid[w][lane] = a1;
    __syncthreads();

    if (lane < NUM_CLASS) {
        float o = lb[lane];
        #pragma unroll 8
        for (int k = 0; k < DD; ++k)
            o = fmaf(hmid[w][k], lw[k * NUM_CLASS + lane], o);
        out[(size_t)m * NUM_CLASS + lane] = o;
    }
}

// ---------------------------------------------------------------------------
extern "C" void kernel_launch(void* const* d_in, const int* in_sizes, int n_in,
                              void* d_out, int out_size, void* d_ws, size_t ws_size,
                              hipStream_t stream) {
    const float* X            = (const float*)d_in[0];
    const float* edge_value   = (const float*)d_in[1];
    const float* conv_weights = (const float*)d_in[2];
    const float* Ws           = (const float*)d_in[3];
    const float* lin1_w       = (const float*)d_in[4];
    const float* lin1_b       = (const float*)d_in[5];
    const float* lin_w        = (const float*)d_in[6];
    const float* lin_b        = (const float*)d_in[7];
    const int*   edge_index   = (const int*)d_in[8];
    const int*   target_x     = (const int*)d_in[9];
    float* out = (float*)d_out;

    unsigned*       Xp16 = (unsigned*)d_ws;                   // 25.6 MB
    unsigned*       H116 = Xp16 + PLANE2;                     // 25.6 MB
    unsigned short* Wsb  = (unsigned short*)(H116 + PLANE2);  // 32 KB
    int*            offs = (int*)(Wsb + C_CH * W_INF * DD);   // N ints
    int*            rowcnt = offs + N_NODES;                  // NCNT ints
    int2*           edata2 = (int2*)(rowcnt + NCNT);          // NSB*SBPAD int2 (17.6 MB)

    prep_kernel<<<64 + 391, 256, 0, stream>>>(Ws, Wsb, rowcnt);
    count_proj_kernel<<<NPART_BLK + PROJ_BLK, 256, 0, stream>>>(
        edge_index, rowcnt, X, Wsb, Xp16);
    scan_kernel<<<391, 256, 0, stream>>>(rowcnt, offs);
    scatter_kernel<<<NPART_BLK, 256, 0, stream>>>(edge_index, edge_value,
                                                  conv_weights, rowcnt, edata2);
    spmm_gather<<<(N_NODES * 64) / 256, 256, 0, stream>>>(Xp16, H116, offs, edata2);
    tgt_tail_kernel<<<M_TGT / 4, 256, 0, stream>>>(H116, Xp16, offs, edata2,
                                                   conv_weights, target_x,
                                                   lin1_w, lin1_b, lin_w, lin_b, out);
}

// Round 3
// 257.185 us; speedup vs baseline: 1.4726x; 1.4726x over previous
//
#include <hip/hip_runtime.h>

// ---- problem constants (from reference) ----
#define N_NODES   100000
#define T_TYPES   4
#define E_EDGES   400000
#define E4        100000                    // int4 groups per type-array
#define G_TOT     400000                    // total int4 groups = TE_TOT/4
#define C_CH      2
#define W_INF     128
#define DD        64
#define NUM_CLASS 16
#define BETA      0.5f
#define M_TGT     10000

// CSR build tiling: 256-row buckets, LDS-staged partition
#define NBKT      391                       // ceil(100000/256) buckets of 256 rows
#define BROWS     256
#define BPAD      4864                      // slots/bucket (mean 4096, sd 64 -> +12 sigma)
#define CHUNK_G   512                       // int4 groups per partition block (2048 edges)
#define NPART_BLK 782                       // ceil(400000/512)
#define PROJ_BLK  1563                      // ceil(100000/64)

// bf16 planes: u32 at [n*64 + d] = bf16(ch0) | bf16(ch1)<<16
static const size_t PLANE2 = (size_t)N_NODES * DD;    // u32 elements per plane

typedef __attribute__((ext_vector_type(8))) short short8x;   // 8 bf16 (4 VGPRs)
typedef __attribute__((ext_vector_type(4))) float f32x4;     // MFMA C/D

__device__ __forceinline__ unsigned bf16rne(float x) {   // RNE f32 -> bf16 bits
    unsigned u = __float_as_uint(x);
    return (u + 0x7FFFu + ((u >> 16) & 1u)) >> 16;
}
__device__ __forceinline__ unsigned packbf(float a, float b) {
    return bf16rne(a) | (bf16rne(b) << 16);
}
__device__ __forceinline__ float bflo(unsigned u) { return __uint_as_float(u << 16); }
__device__ __forceinline__ float bfhi(unsigned u) { return __uint_as_float(u & 0xFFFF0000u); }

__device__ __forceinline__ void load_filter(const float* cw, int layer,
                                            float* f0, float* f1) {
    float m0 = -1e30f, m1 = -1e30f;
    #pragma unroll
    for (int t = 0; t < T_TYPES; ++t) {
        f0[t] = cw[layer * C_CH * T_TYPES + t];
        f1[t] = cw[layer * C_CH * T_TYPES + T_TYPES + t];
        m0 = fmaxf(m0, f0[t]); m1 = fmaxf(m1, f1[t]);
    }
    float s0 = 0.f, s1 = 0.f;
    #pragma unroll
    for (int t = 0; t < T_TYPES; ++t) {
        f0[t] = __expf(f0[t] - m0); s0 += f0[t];
        f1[t] = __expf(f1[t] - m1); s1 += f1[t];
    }
    #pragma unroll
    for (int t = 0; t < T_TYPES; ++t) { f0[t] /= s0; f1[t] /= s1; }
}

// ---------------------------------------------------------------------------
// prep: Wsb[c][d][k] = bf16(Ws[c][k][d]) (blocks 0..63) + cursor init (64..65)
// ---------------------------------------------------------------------------
__global__ void prep_kernel(const float* __restrict__ Ws,
                            unsigned short* __restrict__ Wsb,
                            int* __restrict__ cursor) {
    int b = blockIdx.x;
    int tid = threadIdx.x;
    if (b < 64) {
        int idx = b * 256 + tid;
        int c   = idx >> 13;
        int rem = idx & 8191;
        int d   = rem >> 7;
        int k   = rem & 127;
        Wsb[idx] = (unsigned short)bf16rne(Ws[c * (W_INF * DD) + k * DD + d]);
    } else {
        int idx = (b - 64) * 256 + tid;
        if (idx < NBKT) cursor[idx] = idx * BPAD;
    }
}

// ---------------------------------------------------------------------------
// Fused: blocks [0, NPART_BLK) partition 2048 edges each into 256-row buckets
// via LDS staging (contiguous per-(block,bucket) fragments -> coalesced-ish
// writes, L2-absorbed). ~25 KB LDS -> 6 blocks/CU.
// Blocks [NPART_BLK, +PROJ_BLK) run the LDS-free MFMA projection.
// record: edata2[pos] = { col | t<<17 | (row&255)<<19 ,
//                         packbf(val*f0_l1[t], val*f1_l1[t]) }
// ---------------------------------------------------------------------------
__global__ __launch_bounds__(256) void build_proj_kernel(
        const int* __restrict__ edge_index,
        const float* __restrict__ edge_value,
        const float* __restrict__ cw,
        int* __restrict__ cursor,
        int2* __restrict__ edata2,
        const float* __restrict__ X,
        const unsigned short* __restrict__ Wsb,
        unsigned* __restrict__ Xp16) {
    __shared__ int cnt[392];
    __shared__ int lbase[392];
    __shared__ int gbase[392];
    __shared__ int2 le[2048];                     // 16 KB
    __shared__ unsigned short lbk[2048];          // 4 KB
    int tid = threadIdx.x;

    if (blockIdx.x < NPART_BLK) {
        // ---------------- partition ----------------
        int p = blockIdx.x;
        for (int j = tid; j < NBKT; j += 256) cnt[j] = 0;
        __syncthreads();

        float f0[T_TYPES], f1[T_TYPES];
        load_filter(cw, 0, f0, f1);

        int px[8], pv[8], rk[8], bk[8];
        int ne = 0;
        #pragma unroll
        for (int g = 0; g < 2; ++g) {
            int idx = p * CHUNK_G + g * 256 + tid;
            if (idx < G_TOT) {
                int t = idx / E4, r = idx - t * E4;
                const int* bptr = edge_index + (size_t)t * 2 * E_EDGES;
                int4   rw = ((const int4*)bptr)[r];
                int4   cl = ((const int4*)(bptr + E_EDGES))[r];
                float4 vv = ((const float4*)(edge_value + (size_t)t * E_EDGES))[r];
                int tb = t << 17;
                int   rr[4] = {rw.x, rw.y, rw.z, rw.w};
                int   cc[4] = {cl.x, cl.y, cl.z, cl.w};
                float vf[4] = {vv.x, vv.y, vv.z, vv.w};
                #pragma unroll
                for (int k = 0; k < 4; ++k) {
                    int b = rr[k] >> 8;
                    px[ne] = cc[k] | tb | ((rr[k] & 255) << 19);
                    pv[ne] = __float_as_int(vf[k]);
                    bk[ne] = b;
                    rk[ne] = atomicAdd(&cnt[b], 1);
                    ++ne;
                }
            }
        }
        __syncthreads();
        if (tid < 64) {                                // scan cnt -> lbase (7/lane)
            int c[7]; int s = 0;
            #pragma unroll
            for (int k = 0; k < 7; ++k) {
                int idx = tid * 7 + k;
                c[k] = (idx < NBKT) ? cnt[idx] : 0;
                s += c[k];
            }
            int inc = s;
            #pragma unroll
            for (int off = 1; off < 64; off <<= 1) {
                int v = __shfl_up(inc, off);
                if (tid >= off) inc += v;
            }
            int base = inc - s;
            #pragma unroll
            for (int k = 0; k < 7; ++k) {
                int idx = tid * 7 + k;
                if (idx < NBKT) lbase[idx] = base;
                base += c[k];
            }
        }
        __syncthreads();
        #pragma unroll
        for (int k = 0; k < 8; ++k) {
            if (k < ne) {
                int slot = lbase[bk[k]] + rk[k];
                le[slot]  = make_int2(px[k], pv[k]);
                lbk[slot] = (unsigned short)bk[k];
            }
        }
        __syncthreads();
        for (int j = tid; j < NBKT; j += 256)
            gbase[j] = cnt[j] ? atomicAdd(&cursor[j], cnt[j]) : 0;
        __syncthreads();
        int ngrp = min(CHUNK_G, G_TOT - p * CHUNK_G);
        int nloc = 4 * ngrp;
        for (int j = tid; j < nloc; j += 256) {
            int b = lbk[j];
            int2 e = le[j];
            int t = (e.x >> 17) & 3;
            float v = __int_as_float(e.y);
            edata2[gbase[b] + (j - lbase[b])] =
                make_int2(e.x, (int)packbf(v * f0[t], v * f1[t]));
        }
    } else {
        // ---------------- MFMA projection (LDS-free) ----------------
        int row0 = (blockIdx.x - NPART_BLK) * 64;
        int wave = tid >> 6, lane = tid & 63;
        int m = lane & 15, q = lane >> 4;
        int arow = row0 + wave * 16 + m;
        const float4* X4 = (const float4*)X;
        union { short8x s; uint4 u; } A[4];
        bool valid = arow < N_NODES;
        #pragma unroll
        for (int ks = 0; ks < 4; ++ks) {
            float4 va = make_float4(0.f, 0.f, 0.f, 0.f), vb = va;
            if (valid) {
                va = X4[(size_t)arow * 32 + ks * 8 + q * 2];
                vb = X4[(size_t)arow * 32 + ks * 8 + q * 2 + 1];
            }
            A[ks].u = make_uint4(packbf(va.x, va.y), packbf(va.z, va.w),
                                 packbf(vb.x, vb.y), packbf(vb.z, vb.w));
        }

        #pragma unroll
        for (int ct = 0; ct < 4; ++ct) {
            f32x4 acc0 = {0.f, 0.f, 0.f, 0.f};
            f32x4 acc1 = {0.f, 0.f, 0.f, 0.f};
            #pragma unroll
            for (int ks = 0; ks < 4; ++ks) {
                short8x B0 = *(const short8x*)(Wsb + (ct * 16 + m) * 128 + ks * 32 + q * 8);
                short8x B1 = *(const short8x*)(Wsb + 8192 + (ct * 16 + m) * 128 + ks * 32 + q * 8);
                acc0 = __builtin_amdgcn_mfma_f32_16x16x32_bf16(A[ks].s, B0, acc0, 0, 0, 0);
                acc1 = __builtin_amdgcn_mfma_f32_16x16x32_bf16(A[ks].s, B1, acc1, 0, 0, 0);
            }
            #pragma unroll
            for (int r = 0; r < 4; ++r) {
                int row = row0 + wave * 16 + q * 4 + r;
                if (row < N_NODES)
                    Xp16[(size_t)row * DD + ct * 16 + m] = packbf(acc0[r], acc1[r]);
            }
        }
    }
}

// ---------------------------------------------------------------------------
// Quarter-wave bf16 gather helpers: s16 = lane&15 covers d = {4s..4s+3} both
// channels as uint4 = 16 B/lane; sub = lane>>4 interleaves 4 edges per wave.
// ---------------------------------------------------------------------------
__device__ __forceinline__ void qfma(const uint4 h, unsigned wp,
                                     float4& a, float4& b) {
    float w0 = bflo(wp), w1 = bfhi(wp);
    a.x = fmaf(w0, bflo(h.x), a.x);
    a.y = fmaf(w1, bfhi(h.x), a.y);
    a.z = fmaf(w0, bflo(h.y), a.z);
    a.w = fmaf(w1, bfhi(h.y), a.w);
    b.x = fmaf(w0, bflo(h.z), b.x);
    b.y = fmaf(w1, bfhi(h.z), b.y);
    b.z = fmaf(w0, bflo(h.w), b.z);
    b.w = fmaf(w1, bfhi(h.w), b.w);
}

__device__ __forceinline__ void qreduce(float4& a, float4& b) {
    a.x += __shfl_xor(a.x, 16); a.y += __shfl_xor(a.y, 16);
    a.z += __shfl_xor(a.z, 16); a.w += __shfl_xor(a.w, 16);
    b.x += __shfl_xor(b.x, 16); b.y += __shfl_xor(b.y, 16);
    b.z += __shfl_xor(b.z, 16); b.w += __shfl_xor(b.w, 16);
    a.x += __shfl_xor(a.x, 32); a.y += __shfl_xor(a.y, 32);
    a.z += __shfl_xor(a.z, 32); a.w += __shfl_xor(a.w, 32);
    b.x += __shfl_xor(b.x, 32); b.y += __shfl_xor(b.y, 32);
    b.z += __shfl_xor(b.z, 32); b.w += __shfl_xor(b.w, 32);
}

__device__ __forceinline__ int row_beg(const int* offs, int row) {
    return ((row & 255) == 0) ? (row >> 8) * BPAD : offs[row - 1];
}

// ---------------------------------------------------------------------------
// Fused per-bucket (256 rows) row-sort + layer-1 gather, 512 threads.
//  - load edges into LDS + count rows (one pass)
//  - scan 256 counts (wave 0)
//  - permute: write sorted records to GLOBAL (needed by tgt_tail; L2-absorbed)
//    while recording the permutation in 16-bit LDS index sidx[pos]=j
//  - gather reads edge records from LDS via sidx (broadcast, conflict-free)
// 50.5 KB LDS -> 3 blocks/CU = 24 waves/CU.
// ---------------------------------------------------------------------------
__global__ __launch_bounds__(512) void sortgather_kernel(
        const int* __restrict__ cursor,
        int2* __restrict__ edata2,
        int* __restrict__ offs,
        const unsigned* __restrict__ Hin16,
        unsigned* __restrict__ Hout16) {
    __shared__ int rcnt[BROWS];
    __shared__ int rbase[BROWS];
    __shared__ int rcur[BROWS];
    __shared__ int2 ls[BPAD];                     // 38912 B
    __shared__ unsigned short sidx[BPAD];         // 9728 B
    int b   = blockIdx.x;
    int tid = threadIdx.x;
    int bb  = b * BPAD;
    int cnt = cursor[b] - bb;

    if (tid < BROWS) rcnt[tid] = 0;
    __syncthreads();
    for (int j = tid; j < cnt; j += 512) {
        int2 e = edata2[bb + j];
        ls[j] = e;
        atomicAdd(&rcnt[(e.x >> 19) & 255], 1);
    }
    __syncthreads();
    if (tid < 64) {                                // scan 256 row counts
        int c[4]; int s = 0;
        #pragma unroll
        for (int k = 0; k < 4; ++k) { c[k] = rcnt[tid * 4 + k]; s += c[k]; }
        int inc = s;
        #pragma unroll
        for (int off = 1; off < 64; off <<= 1) {
            int v = __shfl_up(inc, off);
            if (tid >= off) inc += v;
        }
        int base = inc - s;
        #pragma unroll
        for (int k = 0; k < 4; ++k) { rbase[tid * 4 + k] = base; base += c[k]; }
    }
    __syncthreads();
    if (tid < BROWS) rcur[tid] = rbase[tid];
    __syncthreads();
    for (int j = tid; j < cnt; j += 512) {
        int2 e = ls[j];
        int lr = (e.x >> 19) & 255;
        int pos = atomicAdd(&rcur[lr], 1);
        edata2[bb + pos] = e;                     // sorted copy for tgt_tail
        sidx[pos] = (unsigned short)j;            // LDS permutation for gather
    }
    int row0 = b * BROWS;
    if (tid < BROWS && row0 + tid < N_NODES)
        offs[row0 + tid] = bb + rbase[tid] + rcnt[tid];
    __syncthreads();

    // ---------------- layer-1 gather (8 waves x 32 rows) ----------------
    int wv = tid >> 6, lane = tid & 63;
    int s16 = lane & 15, sub = lane >> 4;
    const uint4* hp = (const uint4*)Hin16;
    #pragma unroll 1
    for (int r32 = 0; r32 < 32; ++r32) {
        int lr = wv * 32 + r32;
        int row = row0 + lr;
        int beg = rbase[lr];
        int end = beg + rcnt[lr];
        float4 a = make_float4(0.f, 0.f, 0.f, 0.f);
        float4 bb4 = make_float4(0.f, 0.f, 0.f, 0.f);
        int i = beg + sub;
        for (; i + 4 < end; i += 8) {             // 2 edges per quarter per iter
            int j0 = sidx[i];
            int j1 = sidx[i + 4];
            int2 e0 = ls[j0];
            int2 e1 = ls[j1];
            uint4 h0 = hp[(size_t)(e0.x & 0x1FFFF) * 16 + s16];
            uint4 h1 = hp[(size_t)(e1.x & 0x1FFFF) * 16 + s16];
            qfma(h0, (unsigned)e0.y, a, bb4);
            qfma(h1, (unsigned)e1.y, a, bb4);
        }
        if (i < end) {
            int2 e = ls[sidx[i]];
            uint4 h = hp[(size_t)(e.x & 0x1FFFF) * 16 + s16];
            qfma(h, (unsigned)e.y, a, bb4);
        }
        qreduce(a, bb4);
        if (sub == 0 && row < N_NODES)
            ((uint4*)Hout16)[(size_t)row * 16 + s16] =
                make_uint4(packbf(a.x, a.y), packbf(a.z, a.w),
                           packbf(bb4.x, bb4.y), packbf(bb4.z, bb4.w));
    }
}

// ---------------------------------------------------------------------------
// Fused layer-2 gather (target rows) + tail MLP. Block = 8 waves = 8 targets.
// Layer-2 edge weights = stored_l1_weight * (f_l2[t]/f_l1[t]).
// ---------------------------------------------------------------------------
__global__ __launch_bounds__(512) void tgt_tail_kernel(const unsigned* __restrict__ Hin16,
                                                       const unsigned* __restrict__ Xp16,
                                                       const int* __restrict__ offs,
                                                       const int2* __restrict__ edata2,
                                                       const float* __restrict__ cw,
                                                       const int* __restrict__ tgt,
                                                       const float* __restrict__ lin1_w,
                                                       const float* __restrict__ lin1_b,
                                                       const float* __restrict__ lin_w,
                                                       const float* __restrict__ lin_b,
                                                       float* __restrict__ out) {
    __shared__ float l1w[W_INF * DD];        // 32 KB
    __shared__ float lw[DD * NUM_CLASS];     // 4 KB
    __shared__ float l1b[DD];
    __shared__ float lb[NUM_CLASS];
    __shared__ float hc[8][W_INF];
    __shared__ float hmid[8][DD];

    int tid = threadIdx.x;
    {
        const float4* g = (const float4*)lin1_w;
        float4* s = (float4*)l1w;
        #pragma unroll
        for (int i = 0; i < 4; ++i) s[tid + 512 * i] = g[tid + 512 * i];
        if (tid < 256) ((float4*)lw)[tid] = ((const float4*)lin_w)[tid];
        else if (tid < 256 + DD) l1b[tid - 256] = lin1_b[tid - 256];
        else if (tid < 256 + DD + NUM_CLASS) lb[tid - 256 - DD] = lin_b[tid - 256 - DD];
    }

    float f0a[T_TYPES], f1a[T_TYPES], f0b[T_TYPES], f1b[T_TYPES];
    load_filter(cw, 0, f0a, f1a);
    load_filter(cw, 1, f0b, f1b);
    float r0[T_TYPES], r1[T_TYPES];
    #pragma unroll
    for (int t = 0; t < T_TYPES; ++t) { r0[t] = f0b[t] / f0a[t]; r1[t] = f1b[t] / f1a[t]; }

    int w = tid >> 6, lane = tid & 63;
    int s16 = lane & 15, sub = lane >> 4;
    int m = blockIdx.x * 8 + w;               // M = 10000 = 1250*8
    int row = tgt[m];
    int beg = row_beg(offs, row);
    int end = offs[row];
    const uint4* hp = (const uint4*)Hin16;
    float4 a = make_float4(0.f, 0.f, 0.f, 0.f);
    float4 b = make_float4(0.f, 0.f, 0.f, 0.f);
    for (int i = beg + sub; i < end; i += 4) {
        int2 e = edata2[i];
        int t = (e.x >> 17) & 3;
        uint4 h = hp[(size_t)(e.x & 0x1FFFF) * 16 + s16];
        unsigned wp = (unsigned)e.y;
        float w0 = bflo(wp) * r0[t], w1 = bfhi(wp) * r1[t];
        a.x = fmaf(w0, bflo(h.x), a.x);
        a.y = fmaf(w1, bfhi(h.x), a.y);
        a.z = fmaf(w0, bflo(h.y), a.z);
        a.w = fmaf(w1, bfhi(h.y), a.w);
        b.x = fmaf(w0, bflo(h.z), b.x);
        b.y = fmaf(w1, bfhi(h.z), b.y);
        b.z = fmaf(w0, bflo(h.w), b.z);
        b.w = fmaf(w1, bfhi(h.w), b.w);
    }
    qreduce(a, b);

    if (sub == 0) {
        uint4 xu = ((const uint4*)Xp16)[(size_t)row * 16 + s16];
        int d0 = 4 * s16;
        hc[w][d0 + 0]      = fmaxf(BETA * bflo(xu.x) + (1.f - BETA) * a.x, 0.f);
        hc[w][DD + d0 + 0] = fmaxf(BETA * bfhi(xu.x) + (1.f - BETA) * a.y, 0.f);
        hc[w][d0 + 1]      = fmaxf(BETA * bflo(xu.y) + (1.f - BETA) * a.z, 0.f);
        hc[w][DD + d0 + 1] = fmaxf(BETA * bfhi(xu.y) + (1.f - BETA) * a.w, 0.f);
        hc[w][d0 + 2]      = fmaxf(BETA * bflo(xu.z) + (1.f - BETA) * b.x, 0.f);
        hc[w][DD + d0 + 2] = fmaxf(BETA * bfhi(xu.z) + (1.f - BETA) * b.y, 0.f);
        hc[w][d0 + 3]      = fmaxf(BETA * bflo(xu.w) + (1.f - BETA) * b.z, 0.f);
        hc[w][DD + d0 + 3] = fmaxf(BETA * bfhi(xu.w) + (1.f - BETA) * b.w, 0.f);
    }
    __syncthreads();

    float a1 = l1b[lane];
    #pragma unroll 8
    for (int k = 0; k < W_INF; ++k)
        a1 = fmaf(hc[w][k], l1w[k * DD + lane], a1);
    hmid[w][lane] = a1;
    __syncthreads();

    if (lane < NUM_CLASS) {
        float o = lb[lane];
        #pragma unroll 8
        for (int k = 0; k < DD; ++k)
            o = fmaf(hmid[w][k], lw[k * NUM_CLASS + lane], o);
        out[(size_t)m * NUM_CLASS + lane] = o;
    }
}

// ---------------------------------------------------------------------------
extern "C" void kernel_launch(void* const* d_in, const int* in_sizes, int n_in,
                              void* d_out, int out_size, void* d_ws, size_t ws_size,
                              hipStream_t stream) {
    const float* X            = (const float*)d_in[0];
    const float* edge_value   = (const float*)d_in[1];
    const float* conv_weights = (const float*)d_in[2];
    const float* Ws           = (const float*)d_in[3];
    const float* lin1_w       = (const float*)d_in[4];
    const float* lin1_b       = (const float*)d_in[5];
    const float* lin_w        = (const float*)d_in[6];
    const float* lin_b        = (const float*)d_in[7];
    const int*   edge_index   = (const int*)d_in[8];
    const int*   target_x     = (const int*)d_in[9];
    float* out = (float*)d_out;

    unsigned*       Xp16 = (unsigned*)d_ws;                   // 25.6 MB
    unsigned*       H116 = Xp16 + PLANE2;                     // 25.6 MB
    unsigned short* Wsb  = (unsigned short*)(H116 + PLANE2);  // 32 KB
    int*            offs = (int*)(Wsb + C_CH * W_INF * DD);   // N ints
    int*            cursor = offs + N_NODES;                  // 512
    int2*           edata2 = (int2*)(cursor + 512);           // NBKT*BPAD int2 (15.2 MB)

    prep_kernel<<<66, 256, 0, stream>>>(Ws, Wsb, cursor);
    build_proj_kernel<<<NPART_BLK + PROJ_BLK, 256, 0, stream>>>(
        edge_index, edge_value, conv_weights, cursor, edata2, X, Wsb, Xp16);
    sortgather_kernel<<<NBKT, 512, 0, stream>>>(cursor, edata2, offs, Xp16, H116);
    tgt_tail_kernel<<<M_TGT / 8, 512, 0, stream>>>(H116, Xp16, offs, edata2,
                                                   conv_weights, target_x,
                                                   lin1_w, lin1_b, lin_w, lin_b, out);
}

// Round 4
// 254.549 us; speedup vs baseline: 1.4878x; 1.0104x over previous
//
#include <hip/hip_runtime.h>

// ---- problem constants (from reference) ----
#define N_NODES   100000
#define T_TYPES   4
#define E_EDGES   400000
#define E4        100000                    // int4 groups per type-array
#define G_TOT     400000                    // total int4 groups = TE_TOT/4
#define C_CH      2
#define W_INF     128
#define DD        64
#define NUM_CLASS 16
#define BETA      0.5f
#define M_TGT     10000

// CSR build tiling: 256-row buckets (partition), 64-row quadrants (sort/gather)
#define NBKT      391                       // ceil(100000/256) buckets of 256 rows
#define BROWS     256
#define BPAD      4864                      // unsorted slots/bucket (mean 4096 +12 sigma)
#define QPAD      1216                      // sorted slots/quadrant (mean 1024 +6 sigma)
#define CHUNK_G   512                       // int4 groups per partition block (2048 edges)
#define NPART_BLK 782                       // ceil(400000/512)
#define PROJ_BLK  1563                      // ceil(100000/64)

// bf16 planes: u32 at [n*64 + d] = bf16(ch0) | bf16(ch1)<<16
static const size_t PLANE2 = (size_t)N_NODES * DD;    // u32 elements per plane

typedef __attribute__((ext_vector_type(8))) short short8x;   // 8 bf16 (4 VGPRs)
typedef __attribute__((ext_vector_type(4))) float f32x4;     // MFMA C/D

__device__ __forceinline__ unsigned bf16rne(float x) {   // RNE f32 -> bf16 bits
    unsigned u = __float_as_uint(x);
    return (u + 0x7FFFu + ((u >> 16) & 1u)) >> 16;
}
__device__ __forceinline__ unsigned packbf(float a, float b) {
    return bf16rne(a) | (bf16rne(b) << 16);
}
__device__ __forceinline__ float bflo(unsigned u) { return __uint_as_float(u << 16); }
__device__ __forceinline__ float bfhi(unsigned u) { return __uint_as_float(u & 0xFFFF0000u); }

__device__ __forceinline__ void load_filter(const float* cw, int layer,
                                            float* f0, float* f1) {
    float m0 = -1e30f, m1 = -1e30f;
    #pragma unroll
    for (int t = 0; t < T_TYPES; ++t) {
        f0[t] = cw[layer * C_CH * T_TYPES + t];
        f1[t] = cw[layer * C_CH * T_TYPES + T_TYPES + t];
        m0 = fmaxf(m0, f0[t]); m1 = fmaxf(m1, f1[t]);
    }
    float s0 = 0.f, s1 = 0.f;
    #pragma unroll
    for (int t = 0; t < T_TYPES; ++t) {
        f0[t] = __expf(f0[t] - m0); s0 += f0[t];
        f1[t] = __expf(f1[t] - m1); s1 += f1[t];
    }
    #pragma unroll
    for (int t = 0; t < T_TYPES; ++t) { f0[t] /= s0; f1[t] /= s1; }
}

// ---------------------------------------------------------------------------
// prep: Wsb[c][d][k] = bf16(Ws[c][k][d]) (blocks 0..63) + cursor init (64..65)
// ---------------------------------------------------------------------------
__global__ void prep_kernel(const float* __restrict__ Ws,
                            unsigned short* __restrict__ Wsb,
                            int* __restrict__ cursor) {
    int b = blockIdx.x;
    int tid = threadIdx.x;
    if (b < 64) {
        int idx = b * 256 + tid;
        int c   = idx >> 13;
        int rem = idx & 8191;
        int d   = rem >> 7;
        int k   = rem & 127;
        Wsb[idx] = (unsigned short)bf16rne(Ws[c * (W_INF * DD) + k * DD + d]);
    } else {
        int idx = (b - 64) * 256 + tid;
        if (idx < NBKT) cursor[idx] = idx * BPAD;
    }
}

// ---------------------------------------------------------------------------
// Fused: blocks [0, NPART_BLK) partition 2048 edges each into 256-row buckets
// via LDS staging (contiguous per-(block,bucket) fragments -> coalesced-ish
// writes). ~26 KB LDS -> 6 blocks/CU.
// Blocks [NPART_BLK, +PROJ_BLK) run the LDS-free MFMA projection.
// record: edata2[pos] = { col | t<<17 | (row&255)<<19 ,
//                         packbf(val*f0_l1[t], val*f1_l1[t]) }
// ---------------------------------------------------------------------------
__global__ __launch_bounds__(256) void build_proj_kernel(
        const int* __restrict__ edge_index,
        const float* __restrict__ edge_value,
        const float* __restrict__ cw,
        int* __restrict__ cursor,
        int2* __restrict__ edata2,
        const float* __restrict__ X,
        const unsigned short* __restrict__ Wsb,
        unsigned* __restrict__ Xp16) {
    __shared__ int cnt[392];
    __shared__ int lbase[392];
    __shared__ int gbase[392];
    __shared__ int2 le[2048];                     // 16 KB
    __shared__ unsigned short lbk[2048];          // 4 KB
    int tid = threadIdx.x;

    if (blockIdx.x < NPART_BLK) {
        // ---------------- partition ----------------
        int p = blockIdx.x;
        for (int j = tid; j < NBKT; j += 256) cnt[j] = 0;
        __syncthreads();

        float f0[T_TYPES], f1[T_TYPES];
        load_filter(cw, 0, f0, f1);

        int px[8], pv[8], rk[8], bk[8];
        int ne = 0;
        #pragma unroll
        for (int g = 0; g < 2; ++g) {
            int idx = p * CHUNK_G + g * 256 + tid;
            if (idx < G_TOT) {
                int t = idx / E4, r = idx - t * E4;
                const int* bptr = edge_index + (size_t)t * 2 * E_EDGES;
                int4   rw = ((const int4*)bptr)[r];
                int4   cl = ((const int4*)(bptr + E_EDGES))[r];
                float4 vv = ((const float4*)(edge_value + (size_t)t * E_EDGES))[r];
                int tb = t << 17;
                int   rr[4] = {rw.x, rw.y, rw.z, rw.w};
                int   cc[4] = {cl.x, cl.y, cl.z, cl.w};
                float vf[4] = {vv.x, vv.y, vv.z, vv.w};
                #pragma unroll
                for (int k = 0; k < 4; ++k) {
                    int b = rr[k] >> 8;
                    px[ne] = cc[k] | tb | ((rr[k] & 255) << 19);
                    pv[ne] = __float_as_int(vf[k]);
                    bk[ne] = b;
                    rk[ne] = atomicAdd(&cnt[b], 1);
                    ++ne;
                }
            }
        }
        __syncthreads();
        if (tid < 64) {                                // scan cnt -> lbase (7/lane)
            int c[7]; int s = 0;
            #pragma unroll
            for (int k = 0; k < 7; ++k) {
                int idx = tid * 7 + k;
                c[k] = (idx < NBKT) ? cnt[idx] : 0;
                s += c[k];
            }
            int inc = s;
            #pragma unroll
            for (int off = 1; off < 64; off <<= 1) {
                int v = __shfl_up(inc, off);
                if (tid >= off) inc += v;
            }
            int base = inc - s;
            #pragma unroll
            for (int k = 0; k < 7; ++k) {
                int idx = tid * 7 + k;
                if (idx < NBKT) lbase[idx] = base;
                base += c[k];
            }
        }
        __syncthreads();
        #pragma unroll
        for (int k = 0; k < 8; ++k) {
            if (k < ne) {
                int slot = lbase[bk[k]] + rk[k];
                le[slot]  = make_int2(px[k], pv[k]);
                lbk[slot] = (unsigned short)bk[k];
            }
        }
        __syncthreads();
        for (int j = tid; j < NBKT; j += 256)
            gbase[j] = cnt[j] ? atomicAdd(&cursor[j], cnt[j]) : 0;
        __syncthreads();
        int ngrp = min(CHUNK_G, G_TOT - p * CHUNK_G);
        int nloc = 4 * ngrp;
        for (int j = tid; j < nloc; j += 256) {
            int b = lbk[j];
            int2 e = le[j];
            int t = (e.x >> 17) & 3;
            float v = __int_as_float(e.y);
            edata2[gbase[b] + (j - lbase[b])] =
                make_int2(e.x, (int)packbf(v * f0[t], v * f1[t]));
        }
    } else {
        // ---------------- MFMA projection (LDS-free) ----------------
        int row0 = (blockIdx.x - NPART_BLK) * 64;
        int wave = tid >> 6, lane = tid & 63;
        int m = lane & 15, q = lane >> 4;
        int arow = row0 + wave * 16 + m;
        const float4* X4 = (const float4*)X;
        union { short8x s; uint4 u; } A[4];
        bool valid = arow < N_NODES;
        #pragma unroll
        for (int ks = 0; ks < 4; ++ks) {
            float4 va = make_float4(0.f, 0.f, 0.f, 0.f), vb = va;
            if (valid) {
                va = X4[(size_t)arow * 32 + ks * 8 + q * 2];
                vb = X4[(size_t)arow * 32 + ks * 8 + q * 2 + 1];
            }
            A[ks].u = make_uint4(packbf(va.x, va.y), packbf(va.z, va.w),
                                 packbf(vb.x, vb.y), packbf(vb.z, vb.w));
        }

        #pragma unroll
        for (int ct = 0; ct < 4; ++ct) {
            f32x4 acc0 = {0.f, 0.f, 0.f, 0.f};
            f32x4 acc1 = {0.f, 0.f, 0.f, 0.f};
            #pragma unroll
            for (int ks = 0; ks < 4; ++ks) {
                short8x B0 = *(const short8x*)(Wsb + (ct * 16 + m) * 128 + ks * 32 + q * 8);
                short8x B1 = *(const short8x*)(Wsb + 8192 + (ct * 16 + m) * 128 + ks * 32 + q * 8);
                acc0 = __builtin_amdgcn_mfma_f32_16x16x32_bf16(A[ks].s, B0, acc0, 0, 0, 0);
                acc1 = __builtin_amdgcn_mfma_f32_16x16x32_bf16(A[ks].s, B1, acc1, 0, 0, 0);
            }
            #pragma unroll
            for (int r = 0; r < 4; ++r) {
                int row = row0 + wave * 16 + q * 4 + r;
                if (row < N_NODES)
                    Xp16[(size_t)row * DD + ct * 16 + m] = packbf(acc0[r], acc1[r]);
            }
        }
    }
}

// ---------------------------------------------------------------------------
// Quarter-wave bf16 gather helpers
// ---------------------------------------------------------------------------
__device__ __forceinline__ void qfma(const uint4 h, unsigned wp,
                                     float4& a, float4& b) {
    float w0 = bflo(wp), w1 = bfhi(wp);
    a.x = fmaf(w0, bflo(h.x), a.x);
    a.y = fmaf(w1, bfhi(h.x), a.y);
    a.z = fmaf(w0, bflo(h.y), a.z);
    a.w = fmaf(w1, bfhi(h.y), a.w);
    b.x = fmaf(w0, bflo(h.z), b.x);
    b.y = fmaf(w1, bfhi(h.z), b.y);
    b.z = fmaf(w0, bflo(h.w), b.z);
    b.w = fmaf(w1, bfhi(h.w), b.w);
}

__device__ __forceinline__ void qreduce(float4& a, float4& b) {
    a.x += __shfl_xor(a.x, 16); a.y += __shfl_xor(a.y, 16);
    a.z += __shfl_xor(a.z, 16); a.w += __shfl_xor(a.w, 16);
    b.x += __shfl_xor(b.x, 16); b.y += __shfl_xor(b.y, 16);
    b.z += __shfl_xor(b.z, 16); b.w += __shfl_xor(b.w, 16);
    a.x += __shfl_xor(a.x, 32); a.y += __shfl_xor(a.y, 32);
    a.z += __shfl_xor(a.z, 32); a.w += __shfl_xor(a.w, 32);
    b.x += __shfl_xor(b.x, 32); b.y += __shfl_xor(b.y, 32);
    b.z += __shfl_xor(b.z, 32); b.w += __shfl_xor(b.w, 32);
}

__device__ __forceinline__ int row_beg(const int* offs, int row) {
    return ((row & 63) == 0) ? (row >> 6) * QPAD : offs[row - 1];
}

// ---------------------------------------------------------------------------
// Per-QUADRANT (64 rows of a 256-row bucket) sort + layer-1 gather.
// 4 blocks/bucket; each reads the full bucket from L2, keeps its quarter,
// sorts by row in LDS (permutation sidx), writes sorted quadrant coalesced
// to edataS[s*QPAD ...], then gathers from LDS.  ~13.5 KB LDS, 256 threads
// -> 8 blocks/CU cap; grid 4*392 (mapping b = blockIdx%392 keeps a bucket's
// quadrants on one XCD since 392 % 8 == 0).
// ---------------------------------------------------------------------------
__global__ __launch_bounds__(256) void sortgather_kernel(
        const int* __restrict__ cursor,
        const int2* __restrict__ edata2,
        int2* __restrict__ edataS,
        int* __restrict__ offs,
        const unsigned* __restrict__ Hin16,
        unsigned* __restrict__ Hout16) {
    __shared__ int rcnt[64];
    __shared__ int rbase[64];
    __shared__ int rcur[64];
    __shared__ int nq;
    __shared__ int2 ls[QPAD];                     // 9728 B
    __shared__ unsigned short sidx[QPAD];         // 2432 B
    int b = blockIdx.x % 392;
    int q = blockIdx.x / 392;
    if (b >= NBKT) return;
    int tid = threadIdx.x;
    int bb  = b * BPAD;
    int cnt = cursor[b] - bb;

    if (tid < 64) rcnt[tid] = 0;
    if (tid == 0) nq = 0;
    __syncthreads();
    for (int j = tid; j < cnt; j += 256) {
        int2 e = edata2[bb + j];
        int rt = (e.x >> 19) & 255;
        if ((rt >> 6) == q) {
            int pos = atomicAdd(&nq, 1);
            if (pos < QPAD) {
                ls[pos] = e;
                atomicAdd(&rcnt[rt & 63], 1);
            }
        }
    }
    __syncthreads();
    int nl = min(nq, QPAD);
    if (tid < 64) {                                // scan 64 row counts (wave 0)
        int c = rcnt[tid];
        int inc = c;
        #pragma unroll
        for (int off = 1; off < 64; off <<= 1) {
            int v = __shfl_up(inc, off);
            if (tid >= off) inc += v;
        }
        rbase[tid] = inc - c;
        rcur[tid]  = inc - c;
    }
    __syncthreads();
    for (int j = tid; j < nl; j += 256) {
        int lr = (ls[j].x >> 19) & 63;
        int pos = atomicAdd(&rcur[lr], 1);
        sidx[pos] = (unsigned short)j;
    }
    __syncthreads();

    int s  = b * 4 + q;                           // global 64-row sub-bucket id
    int sb = s * QPAD;
    for (int i = tid; i < nl; i += 256)           // coalesced sorted write-back
        edataS[sb + i] = ls[sidx[i]];
    int row0 = s * 64;
    if (tid < 64 && row0 + tid < N_NODES)
        offs[row0 + tid] = sb + rbase[tid] + rcnt[tid];

    // ---------------- layer-1 gather (4 waves x 16 rows) ----------------
    int wv = tid >> 6, lane = tid & 63;
    int s16 = lane & 15, sub = lane >> 4;
    const uint4* hp = (const uint4*)Hin16;
    #pragma unroll 1
    for (int r16 = 0; r16 < 16; ++r16) {
        int lr = wv * 16 + r16;
        int row = row0 + lr;
        int beg = rbase[lr];
        int end = beg + rcnt[lr];
        float4 a  = make_float4(0.f, 0.f, 0.f, 0.f);
        float4 b4 = make_float4(0.f, 0.f, 0.f, 0.f);
        int i = beg + sub;
        for (; i + 4 < end; i += 8) {             // 2 edges per quarter per iter
            int2 e0 = ls[sidx[i]];
            int2 e1 = ls[sidx[i + 4]];
            uint4 h0 = hp[(size_t)(e0.x & 0x1FFFF) * 16 + s16];
            uint4 h1 = hp[(size_t)(e1.x & 0x1FFFF) * 16 + s16];
            qfma(h0, (unsigned)e0.y, a, b4);
            qfma(h1, (unsigned)e1.y, a, b4);
        }
        if (i < end) {
            int2 e = ls[sidx[i]];
            uint4 h = hp[(size_t)(e.x & 0x1FFFF) * 16 + s16];
            qfma(h, (unsigned)e.y, a, b4);
        }
        qreduce(a, b4);
        if (sub == 0 && row < N_NODES)
            ((uint4*)Hout16)[(size_t)row * 16 + s16] =
                make_uint4(packbf(a.x, a.y), packbf(a.z, a.w),
                           packbf(b4.x, b4.y), packbf(b4.z, b4.w));
    }
}

// ---------------------------------------------------------------------------
// Fused layer-2 gather (target rows) + tail MLP. Block = 4 waves = 4 targets.
// Weights read straight through L1 (lin1_w = 32 KB fits L1; no staging).
// Layer-2 edge weights = stored_l1_weight * (f_l2[t]/f_l1[t]).
// ---------------------------------------------------------------------------
__global__ __launch_bounds__(256) void tgt_tail_kernel(const unsigned* __restrict__ Hin16,
                                                       const unsigned* __restrict__ Xp16,
                                                       const int* __restrict__ offs,
                                                       const int2* __restrict__ edataS,
                                                       const float* __restrict__ cw,
                                                       const int* __restrict__ tgt,
                                                       const float* __restrict__ lin1_w,
                                                       const float* __restrict__ lin1_b,
                                                       const float* __restrict__ lin_w,
                                                       const float* __restrict__ lin_b,
                                                       float* __restrict__ out) {
    __shared__ float hc[4][W_INF];
    __shared__ float hmid[4][DD];

    int tid = threadIdx.x;

    float f0a[T_TYPES], f1a[T_TYPES], f0b[T_TYPES], f1b[T_TYPES];
    load_filter(cw, 0, f0a, f1a);
    load_filter(cw, 1, f0b, f1b);
    float r0[T_TYPES], r1[T_TYPES];
    #pragma unroll
    for (int t = 0; t < T_TYPES; ++t) { r0[t] = f0b[t] / f0a[t]; r1[t] = f1b[t] / f1a[t]; }

    int w = tid >> 6, lane = tid & 63;
    int s16 = lane & 15, sub = lane >> 4;
    int m = blockIdx.x * 4 + w;               // M = 10000 = 2500*4
    int row = tgt[m];
    int beg = row_beg(offs, row);
    int end = offs[row];
    const uint4* hp = (const uint4*)Hin16;
    float4 a = make_float4(0.f, 0.f, 0.f, 0.f);
    float4 b = make_float4(0.f, 0.f, 0.f, 0.f);
    for (int i = beg + sub; i < end; i += 4) {
        int2 e = edataS[i];
        int t = (e.x >> 17) & 3;
        uint4 h = hp[(size_t)(e.x & 0x1FFFF) * 16 + s16];
        unsigned wp = (unsigned)e.y;
        float w0 = bflo(wp) * r0[t], w1 = bfhi(wp) * r1[t];
        a.x = fmaf(w0, bflo(h.x), a.x);
        a.y = fmaf(w1, bfhi(h.x), a.y);
        a.z = fmaf(w0, bflo(h.y), a.z);
        a.w = fmaf(w1, bfhi(h.y), a.w);
        b.x = fmaf(w0, bflo(h.z), b.x);
        b.y = fmaf(w1, bfhi(h.z), b.y);
        b.z = fmaf(w0, bflo(h.w), b.z);
        b.w = fmaf(w1, bfhi(h.w), b.w);
    }
    qreduce(a, b);

    if (sub == 0) {
        uint4 xu = ((const uint4*)Xp16)[(size_t)row * 16 + s16];
        int d0 = 4 * s16;
        hc[w][d0 + 0]      = fmaxf(BETA * bflo(xu.x) + (1.f - BETA) * a.x, 0.f);
        hc[w][DD + d0 + 0] = fmaxf(BETA * bfhi(xu.x) + (1.f - BETA) * a.y, 0.f);
        hc[w][d0 + 1]      = fmaxf(BETA * bflo(xu.y) + (1.f - BETA) * a.z, 0.f);
        hc[w][DD + d0 + 1] = fmaxf(BETA * bfhi(xu.y) + (1.f - BETA) * a.w, 0.f);
        hc[w][d0 + 2]      = fmaxf(BETA * bflo(xu.z) + (1.f - BETA) * b.x, 0.f);
        hc[w][DD + d0 + 2] = fmaxf(BETA * bfhi(xu.z) + (1.f - BETA) * b.y, 0.f);
        hc[w][d0 + 3]      = fmaxf(BETA * bflo(xu.w) + (1.f - BETA) * b.z, 0.f);
        hc[w][DD + d0 + 3] = fmaxf(BETA * bfhi(xu.w) + (1.f - BETA) * b.w, 0.f);
    }
    __syncthreads();

    float a1 = lin1_b[lane];
    #pragma unroll 8
    for (int k = 0; k < W_INF; ++k)
        a1 = fmaf(hc[w][k], lin1_w[k * DD + lane], a1);
    hmid[w][lane] = a1;
    __syncthreads();

    if (lane < NUM_CLASS) {
        float o = lin_b[lane];
        #pragma unroll 8
        for (int k = 0; k < DD; ++k)
            o = fmaf(hmid[w][k], lin_w[k * NUM_CLASS + lane], o);
        out[(size_t)m * NUM_CLASS + lane] = o;
    }
}

// ---------------------------------------------------------------------------
extern "C" void kernel_launch(void* const* d_in, const int* in_sizes, int n_in,
                              void* d_out, int out_size, void* d_ws, size_t ws_size,
                              hipStream_t stream) {
    const float* X            = (const float*)d_in[0];
    const float* edge_value   = (const float*)d_in[1];
    const float* conv_weights = (const float*)d_in[2];
    const float* Ws           = (const float*)d_in[3];
    const float* lin1_w       = (const float*)d_in[4];
    const float* lin1_b       = (const float*)d_in[5];
    const float* lin_w        = (const float*)d_in[6];
    const float* lin_b        = (const float*)d_in[7];
    const int*   edge_index   = (const int*)d_in[8];
    const int*   target_x     = (const int*)d_in[9];
    float* out = (float*)d_out;

    unsigned*       Xp16 = (unsigned*)d_ws;                   // 25.6 MB
    unsigned*       H116 = Xp16 + PLANE2;                     // 25.6 MB
    unsigned short* Wsb  = (unsigned short*)(H116 + PLANE2);  // 32 KB
    int*            offs = (int*)(Wsb + C_CH * W_INF * DD);   // N ints
    int*            cursor = offs + N_NODES;                  // 512
    int2*           edata2 = (int2*)(cursor + 512);           // NBKT*BPAD int2 (15.2 MB)
    int2*           edataS = edata2 + (size_t)NBKT * BPAD;    // NBKT*4*QPAD int2 (15.2 MB)

    prep_kernel<<<66, 256, 0, stream>>>(Ws, Wsb, cursor);
    build_proj_kernel<<<NPART_BLK + PROJ_BLK, 256, 0, stream>>>(
        edge_index, edge_value, conv_weights, cursor, edata2, X, Wsb, Xp16);
    sortgather_kernel<<<4 * 392, 256, 0, stream>>>(cursor, edata2, edataS, offs,
                                                   Xp16, H116);
    tgt_tail_kernel<<<M_TGT / 4, 256, 0, stream>>>(H116, Xp16, offs, edataS,
                                                   conv_weights, target_x,
                                                   lin1_w, lin1_b, lin_w, lin_b, out);
}

// Round 5
// 253.199 us; speedup vs baseline: 1.4957x; 1.0053x over previous
//
#include <hip/hip_runtime.h>

// ---- problem constants (from reference) ----
#define N_NODES   100000
#define T_TYPES   4
#define E_EDGES   400000
#define E4        100000                    // int4 groups per type-array
#define G_TOT     400000                    // total int4 groups = TE_TOT/4
#define C_CH      2
#define W_INF     128
#define DD        64
#define NUM_CLASS 16
#define BETA      0.5f
#define M_TGT     10000

// CSR build tiling: 256-row buckets (partition), 32-row octants (sort/gather)
#define NBKT      391                       // ceil(100000/256) buckets of 256 rows
#define BROWS     256
#define BPAD      4864                      // unsorted slots/bucket (mean 4096 +12 sigma)
#define QPAD      672                       // sorted slots/octant (mean 512 +7 sigma)
#define CHUNK_G   512                       // int4 groups per partition block (2048 edges)
#define NPART_BLK 782                       // ceil(400000/512)
#define PROJ_BLK  1563                      // ceil(100000/64)

// bf16 planes: u32 at [n*64 + d] = bf16(ch0) | bf16(ch1)<<16
static const size_t PLANE2 = (size_t)N_NODES * DD;    // u32 elements per plane

typedef __attribute__((ext_vector_type(8))) short short8x;   // 8 bf16 (4 VGPRs)
typedef __attribute__((ext_vector_type(4))) float f32x4;     // MFMA C/D

__device__ __forceinline__ unsigned bf16rne(float x) {   // RNE f32 -> bf16 bits
    unsigned u = __float_as_uint(x);
    return (u + 0x7FFFu + ((u >> 16) & 1u)) >> 16;
}
__device__ __forceinline__ unsigned packbf(float a, float b) {
    return bf16rne(a) | (bf16rne(b) << 16);
}
__device__ __forceinline__ float bflo(unsigned u) { return __uint_as_float(u << 16); }
__device__ __forceinline__ float bfhi(unsigned u) { return __uint_as_float(u & 0xFFFF0000u); }

__device__ __forceinline__ void load_filter(const float* cw, int layer,
                                            float* f0, float* f1) {
    float m0 = -1e30f, m1 = -1e30f;
    #pragma unroll
    for (int t = 0; t < T_TYPES; ++t) {
        f0[t] = cw[layer * C_CH * T_TYPES + t];
        f1[t] = cw[layer * C_CH * T_TYPES + T_TYPES + t];
        m0 = fmaxf(m0, f0[t]); m1 = fmaxf(m1, f1[t]);
    }
    float s0 = 0.f, s1 = 0.f;
    #pragma unroll
    for (int t = 0; t < T_TYPES; ++t) {
        f0[t] = __expf(f0[t] - m0); s0 += f0[t];
        f1[t] = __expf(f1[t] - m1); s1 += f1[t];
    }
    #pragma unroll
    for (int t = 0; t < T_TYPES; ++t) { f0[t] /= s0; f1[t] /= s1; }
}

// ---------------------------------------------------------------------------
// prep: Wsb[c][d][k] = bf16(Ws[c][k][d]) (blocks 0..63) + cursor init (64..65)
// ---------------------------------------------------------------------------
__global__ void prep_kernel(const float* __restrict__ Ws,
                            unsigned short* __restrict__ Wsb,
                            int* __restrict__ cursor) {
    int b = blockIdx.x;
    int tid = threadIdx.x;
    if (b < 64) {
        int idx = b * 256 + tid;
        int c   = idx >> 13;
        int rem = idx & 8191;
        int d   = rem >> 7;
        int k   = rem & 127;
        Wsb[idx] = (unsigned short)bf16rne(Ws[c * (W_INF * DD) + k * DD + d]);
    } else {
        int idx = (b - 64) * 256 + tid;
        if (idx < NBKT) cursor[idx] = idx * BPAD;
    }
}

// ---------------------------------------------------------------------------
// Fused: blocks [0, NPART_BLK) partition 2048 edges each into 256-row buckets
// via LDS staging (contiguous per-(block,bucket) fragments -> coalesced-ish
// writes). ~26 KB LDS -> 6 blocks/CU.
// Blocks [NPART_BLK, +PROJ_BLK) run the LDS-free MFMA projection.
// record: edata2[pos] = { col | t<<17 | (row&255)<<19 ,
//                         packbf(val*f0_l1[t], val*f1_l1[t]) }
// ---------------------------------------------------------------------------
__global__ __launch_bounds__(256) void build_proj_kernel(
        const int* __restrict__ edge_index,
        const float* __restrict__ edge_value,
        const float* __restrict__ cw,
        int* __restrict__ cursor,
        int2* __restrict__ edata2,
        const float* __restrict__ X,
        const unsigned short* __restrict__ Wsb,
        unsigned* __restrict__ Xp16) {
    __shared__ int cnt[392];
    __shared__ int lbase[392];
    __shared__ int gbase[392];
    __shared__ int2 le[2048];                     // 16 KB
    __shared__ unsigned short lbk[2048];          // 4 KB
    int tid = threadIdx.x;

    if (blockIdx.x < NPART_BLK) {
        // ---------------- partition ----------------
        int p = blockIdx.x;
        for (int j = tid; j < NBKT; j += 256) cnt[j] = 0;
        __syncthreads();

        float f0[T_TYPES], f1[T_TYPES];
        load_filter(cw, 0, f0, f1);

        int px[8], pv[8], rk[8], bk[8];
        int ne = 0;
        #pragma unroll
        for (int g = 0; g < 2; ++g) {
            int idx = p * CHUNK_G + g * 256 + tid;
            if (idx < G_TOT) {
                int t = idx / E4, r = idx - t * E4;
                const int* bptr = edge_index + (size_t)t * 2 * E_EDGES;
                int4   rw = ((const int4*)bptr)[r];
                int4   cl = ((const int4*)(bptr + E_EDGES))[r];
                float4 vv = ((const float4*)(edge_value + (size_t)t * E_EDGES))[r];
                int tb = t << 17;
                int   rr[4] = {rw.x, rw.y, rw.z, rw.w};
                int   cc[4] = {cl.x, cl.y, cl.z, cl.w};
                float vf[4] = {vv.x, vv.y, vv.z, vv.w};
                #pragma unroll
                for (int k = 0; k < 4; ++k) {
                    int b = rr[k] >> 8;
                    px[ne] = cc[k] | tb | ((rr[k] & 255) << 19);
                    pv[ne] = __float_as_int(vf[k]);
                    bk[ne] = b;
                    rk[ne] = atomicAdd(&cnt[b], 1);
                    ++ne;
                }
            }
        }
        __syncthreads();
        if (tid < 64) {                                // scan cnt -> lbase (7/lane)
            int c[7]; int s = 0;
            #pragma unroll
            for (int k = 0; k < 7; ++k) {
                int idx = tid * 7 + k;
                c[k] = (idx < NBKT) ? cnt[idx] : 0;
                s += c[k];
            }
            int inc = s;
            #pragma unroll
            for (int off = 1; off < 64; off <<= 1) {
                int v = __shfl_up(inc, off);
                if (tid >= off) inc += v;
            }
            int base = inc - s;
            #pragma unroll
            for (int k = 0; k < 7; ++k) {
                int idx = tid * 7 + k;
                if (idx < NBKT) lbase[idx] = base;
                base += c[k];
            }
        }
        __syncthreads();
        #pragma unroll
        for (int k = 0; k < 8; ++k) {
            if (k < ne) {
                int slot = lbase[bk[k]] + rk[k];
                le[slot]  = make_int2(px[k], pv[k]);
                lbk[slot] = (unsigned short)bk[k];
            }
        }
        __syncthreads();
        for (int j = tid; j < NBKT; j += 256)
            gbase[j] = cnt[j] ? atomicAdd(&cursor[j], cnt[j]) : 0;
        __syncthreads();
        int ngrp = min(CHUNK_G, G_TOT - p * CHUNK_G);
        int nloc = 4 * ngrp;
        for (int j = tid; j < nloc; j += 256) {
            int b = lbk[j];
            int2 e = le[j];
            int t = (e.x >> 17) & 3;
            float v = __int_as_float(e.y);
            edata2[gbase[b] + (j - lbase[b])] =
                make_int2(e.x, (int)packbf(v * f0[t], v * f1[t]));
        }
    } else {
        // ---------------- MFMA projection (LDS-free) ----------------
        int row0 = (blockIdx.x - NPART_BLK) * 64;
        int wave = tid >> 6, lane = tid & 63;
        int m = lane & 15, q = lane >> 4;
        int arow = row0 + wave * 16 + m;
        const float4* X4 = (const float4*)X;
        union { short8x s; uint4 u; } A[4];
        bool valid = arow < N_NODES;
        #pragma unroll
        for (int ks = 0; ks < 4; ++ks) {
            float4 va = make_float4(0.f, 0.f, 0.f, 0.f), vb = va;
            if (valid) {
                va = X4[(size_t)arow * 32 + ks * 8 + q * 2];
                vb = X4[(size_t)arow * 32 + ks * 8 + q * 2 + 1];
            }
            A[ks].u = make_uint4(packbf(va.x, va.y), packbf(va.z, va.w),
                                 packbf(vb.x, vb.y), packbf(vb.z, vb.w));
        }

        #pragma unroll
        for (int ct = 0; ct < 4; ++ct) {
            f32x4 acc0 = {0.f, 0.f, 0.f, 0.f};
            f32x4 acc1 = {0.f, 0.f, 0.f, 0.f};
            #pragma unroll
            for (int ks = 0; ks < 4; ++ks) {
                short8x B0 = *(const short8x*)(Wsb + (ct * 16 + m) * 128 + ks * 32 + q * 8);
                short8x B1 = *(const short8x*)(Wsb + 8192 + (ct * 16 + m) * 128 + ks * 32 + q * 8);
                acc0 = __builtin_amdgcn_mfma_f32_16x16x32_bf16(A[ks].s, B0, acc0, 0, 0, 0);
                acc1 = __builtin_amdgcn_mfma_f32_16x16x32_bf16(A[ks].s, B1, acc1, 0, 0, 0);
            }
            #pragma unroll
            for (int r = 0; r < 4; ++r) {
                int row = row0 + wave * 16 + q * 4 + r;
                if (row < N_NODES)
                    Xp16[(size_t)row * DD + ct * 16 + m] = packbf(acc0[r], acc1[r]);
            }
        }
    }
}

// ---------------------------------------------------------------------------
// Quarter-wave bf16 gather helpers
// ---------------------------------------------------------------------------
__device__ __forceinline__ void qfma(const uint4 h, unsigned wp,
                                     float4& a, float4& b) {
    float w0 = bflo(wp), w1 = bfhi(wp);
    a.x = fmaf(w0, bflo(h.x), a.x);
    a.y = fmaf(w1, bfhi(h.x), a.y);
    a.z = fmaf(w0, bflo(h.y), a.z);
    a.w = fmaf(w1, bfhi(h.y), a.w);
    b.x = fmaf(w0, bflo(h.z), b.x);
    b.y = fmaf(w1, bfhi(h.z), b.y);
    b.z = fmaf(w0, bflo(h.w), b.z);
    b.w = fmaf(w1, bfhi(h.w), b.w);
}

__device__ __forceinline__ void qreduce(float4& a, float4& b) {
    a.x += __shfl_xor(a.x, 16); a.y += __shfl_xor(a.y, 16);
    a.z += __shfl_xor(a.z, 16); a.w += __shfl_xor(a.w, 16);
    b.x += __shfl_xor(b.x, 16); b.y += __shfl_xor(b.y, 16);
    b.z += __shfl_xor(b.z, 16); b.w += __shfl_xor(b.w, 16);
    a.x += __shfl_xor(a.x, 32); a.y += __shfl_xor(a.y, 32);
    a.z += __shfl_xor(a.z, 32); a.w += __shfl_xor(a.w, 32);
    b.x += __shfl_xor(b.x, 32); b.y += __shfl_xor(b.y, 32);
    b.z += __shfl_xor(b.z, 32); b.w += __shfl_xor(b.w, 32);
}

__device__ __forceinline__ int row_beg(const int* offs, int row) {
    return ((row & 31) == 0) ? (row >> 5) * QPAD : offs[row - 1];
}

// ---------------------------------------------------------------------------
// Per-OCTANT (32 rows of a 256-row bucket) sort + layer-1 gather.
// 8 blocks/bucket; each reads the full bucket from L2, keeps its eighth,
// permutes into sorted LDS ls2 (no index indirection), writes sorted octant
// coalesced to edataS, then gathers QUARTER-PER-ROW: each 16-lane quarter
// owns a whole row (16 lanes x uint4 = full 64-u32 row), 4-deep edge unroll,
// no cross-lane reduce, 256-B coalesced stores.
// ~11 KB LDS, 256 threads -> 8 blocks/CU (wave cap); grid 8*392
// (b = blockIdx%392 keeps a bucket's octants on one XCD: 392 % 8 == 0).
// ---------------------------------------------------------------------------
__global__ __launch_bounds__(256) void sortgather_kernel(
        const int* __restrict__ cursor,
        const int2* __restrict__ edata2,
        int2* __restrict__ edataS,
        int* __restrict__ offs,
        const unsigned* __restrict__ Hin16,
        unsigned* __restrict__ Hout16) {
    __shared__ int rcnt[32];
    __shared__ int rbase[32];
    __shared__ int rcur[32];
    __shared__ int nq;
    __shared__ int2 ls[QPAD];                     // 5376 B
    __shared__ int2 ls2[QPAD];                    // 5376 B (sorted)
    int b = blockIdx.x % 392;
    int o = blockIdx.x / 392;
    if (b >= NBKT) return;
    int tid = threadIdx.x;
    int bb  = b * BPAD;
    int cnt = cursor[b] - bb;

    if (tid < 32) rcnt[tid] = 0;
    if (tid == 0) nq = 0;
    __syncthreads();
    for (int j = tid; j < cnt; j += 256) {
        int2 e = edata2[bb + j];
        int rt = (e.x >> 19) & 255;
        if ((rt >> 5) == o) {
            int pos = atomicAdd(&nq, 1);
            if (pos < QPAD) {
                ls[pos] = e;
                atomicAdd(&rcnt[rt & 31], 1);
            }
        }
    }
    __syncthreads();
    int nl = min(nq, QPAD);
    if (tid < 32) {                                // scan 32 row counts (wave 0)
        int c = rcnt[tid];
        int inc = c;
        #pragma unroll
        for (int off = 1; off < 32; off <<= 1) {
            int v = __shfl_up(inc, off);
            if (tid >= off) inc += v;
        }
        rbase[tid] = inc - c;
        rcur[tid]  = inc - c;
    }
    __syncthreads();
    for (int j = tid; j < nl; j += 256) {
        int2 e = ls[j];
        int lr = (e.x >> 19) & 31;
        int pos = atomicAdd(&rcur[lr], 1);
        ls2[pos] = e;
    }
    __syncthreads();

    int s  = b * 8 + o;                           // global 32-row octant id
    int sb = s * QPAD;
    for (int i = tid; i < nl; i += 256)           // coalesced sorted write-back
        edataS[sb + i] = ls2[i];
    int row0 = s * 32;
    if (tid < 32 && row0 + tid < N_NODES)
        offs[row0 + tid] = sb + rbase[tid] + rcnt[tid];
    __syncthreads();

    // ---- layer-1 gather: quarter-per-row, 4 waves x (2 rounds x 4 quarters) ----
    int wv = tid >> 6, lane = tid & 63;
    int s16 = lane & 15, qd = lane >> 4;
    const uint4* hp = (const uint4*)Hin16;
    #pragma unroll
    for (int rr = 0; rr < 2; ++rr) {
        int lr  = wv * 8 + rr * 4 + qd;
        int row = row0 + lr;
        int beg = rbase[lr];
        int end = beg + rcnt[lr];
        float4 a  = make_float4(0.f, 0.f, 0.f, 0.f);
        float4 b4 = make_float4(0.f, 0.f, 0.f, 0.f);
        int i = beg;
        for (; i + 3 < end; i += 4) {             // 4 loads in flight per quarter
            int2 e0 = ls2[i];
            int2 e1 = ls2[i + 1];
            int2 e2 = ls2[i + 2];
            int2 e3 = ls2[i + 3];
            uint4 h0 = hp[(size_t)(e0.x & 0x1FFFF) * 16 + s16];
            uint4 h1 = hp[(size_t)(e1.x & 0x1FFFF) * 16 + s16];
            uint4 h2 = hp[(size_t)(e2.x & 0x1FFFF) * 16 + s16];
            uint4 h3 = hp[(size_t)(e3.x & 0x1FFFF) * 16 + s16];
            qfma(h0, (unsigned)e0.y, a, b4);
            qfma(h1, (unsigned)e1.y, a, b4);
            qfma(h2, (unsigned)e2.y, a, b4);
            qfma(h3, (unsigned)e3.y, a, b4);
        }
        if (i + 1 < end) {
            int2 e0 = ls2[i];
            int2 e1 = ls2[i + 1];
            uint4 h0 = hp[(size_t)(e0.x & 0x1FFFF) * 16 + s16];
            uint4 h1 = hp[(size_t)(e1.x & 0x1FFFF) * 16 + s16];
            qfma(h0, (unsigned)e0.y, a, b4);
            qfma(h1, (unsigned)e1.y, a, b4);
            i += 2;
        }
        if (i < end) {
            int2 e = ls2[i];
            uint4 h = hp[(size_t)(e.x & 0x1FFFF) * 16 + s16];
            qfma(h, (unsigned)e.y, a, b4);
        }
        if (row < N_NODES)
            ((uint4*)Hout16)[(size_t)row * 16 + s16] =
                make_uint4(packbf(a.x, a.y), packbf(a.z, a.w),
                           packbf(b4.x, b4.y), packbf(b4.z, b4.w));
    }
}

// ---------------------------------------------------------------------------
// Fused layer-2 gather (target rows) + tail MLP. Block = 4 waves = 4 targets.
// Weights read straight through L1 (lin1_w = 32 KB fits L1; no staging).
// Layer-2 edge weights = stored_l1_weight * (f_l2[t]/f_l1[t]).
// ---------------------------------------------------------------------------
__global__ __launch_bounds__(256) void tgt_tail_kernel(const unsigned* __restrict__ Hin16,
                                                       const unsigned* __restrict__ Xp16,
                                                       const int* __restrict__ offs,
                                                       const int2* __restrict__ edataS,
                                                       const float* __restrict__ cw,
                                                       const int* __restrict__ tgt,
                                                       const float* __restrict__ lin1_w,
                                                       const float* __restrict__ lin1_b,
                                                       const float* __restrict__ lin_w,
                                                       const float* __restrict__ lin_b,
                                                       float* __restrict__ out) {
    __shared__ float hc[4][W_INF];
    __shared__ float hmid[4][DD];

    int tid = threadIdx.x;

    float f0a[T_TYPES], f1a[T_TYPES], f0b[T_TYPES], f1b[T_TYPES];
    load_filter(cw, 0, f0a, f1a);
    load_filter(cw, 1, f0b, f1b);
    float r0[T_TYPES], r1[T_TYPES];
    #pragma unroll
    for (int t = 0; t < T_TYPES; ++t) { r0[t] = f0b[t] / f0a[t]; r1[t] = f1b[t] / f1a[t]; }

    int w = tid >> 6, lane = tid & 63;
    int s16 = lane & 15, sub = lane >> 4;
    int m = blockIdx.x * 4 + w;               // M = 10000 = 2500*4
    int row = tgt[m];
    int beg = row_beg(offs, row);
    int end = offs[row];
    const uint4* hp = (const uint4*)Hin16;
    float4 a = make_float4(0.f, 0.f, 0.f, 0.f);
    float4 b = make_float4(0.f, 0.f, 0.f, 0.f);
    for (int i = beg + sub; i < end; i += 4) {
        int2 e = edataS[i];
        int t = (e.x >> 17) & 3;
        uint4 h = hp[(size_t)(e.x & 0x1FFFF) * 16 + s16];
        unsigned wp = (unsigned)e.y;
        float w0 = bflo(wp) * r0[t], w1 = bfhi(wp) * r1[t];
        a.x = fmaf(w0, bflo(h.x), a.x);
        a.y = fmaf(w1, bfhi(h.x), a.y);
        a.z = fmaf(w0, bflo(h.y), a.z);
        a.w = fmaf(w1, bfhi(h.y), a.w);
        b.x = fmaf(w0, bflo(h.z), b.x);
        b.y = fmaf(w1, bfhi(h.z), b.y);
        b.z = fmaf(w0, bflo(h.w), b.z);
        b.w = fmaf(w1, bfhi(h.w), b.w);
    }
    qreduce(a, b);

    if (sub == 0) {
        uint4 xu = ((const uint4*)Xp16)[(size_t)row * 16 + s16];
        int d0 = 4 * s16;
        hc[w][d0 + 0]      = fmaxf(BETA * bflo(xu.x) + (1.f - BETA) * a.x, 0.f);
        hc[w][DD + d0 + 0] = fmaxf(BETA * bfhi(xu.x) + (1.f - BETA) * a.y, 0.f);
        hc[w][d0 + 1]      = fmaxf(BETA * bflo(xu.y) + (1.f - BETA) * a.z, 0.f);
        hc[w][DD + d0 + 1] = fmaxf(BETA * bfhi(xu.y) + (1.f - BETA) * a.w, 0.f);
        hc[w][d0 + 2]      = fmaxf(BETA * bflo(xu.z) + (1.f - BETA) * b.x, 0.f);
        hc[w][DD + d0 + 2] = fmaxf(BETA * bfhi(xu.z) + (1.f - BETA) * b.y, 0.f);
        hc[w][d0 + 3]      = fmaxf(BETA * bflo(xu.w) + (1.f - BETA) * b.z, 0.f);
        hc[w][DD + d0 + 3] = fmaxf(BETA * bfhi(xu.w) + (1.f - BETA) * b.w, 0.f);
    }
    __syncthreads();

    float a1 = lin1_b[lane];
    #pragma unroll 8
    for (int k = 0; k < W_INF; ++k)
        a1 = fmaf(hc[w][k], lin1_w[k * DD + lane], a1);
    hmid[w][lane] = a1;
    __syncthreads();

    if (lane < NUM_CLASS) {
        float o = lin_b[lane];
        #pragma unroll 8
        for (int k = 0; k < DD; ++k)
            o = fmaf(hmid[w][k], lin_w[k * NUM_CLASS + lane], o);
        out[(size_t)m * NUM_CLASS + lane] = o;
    }
}

// ---------------------------------------------------------------------------
extern "C" void kernel_launch(void* const* d_in, const int* in_sizes, int n_in,
                              void* d_out, int out_size, void* d_ws, size_t ws_size,
                              hipStream_t stream) {
    const float* X            = (const float*)d_in[0];
    const float* edge_value   = (const float*)d_in[1];
    const float* conv_weights = (const float*)d_in[2];
    const float* Ws           = (const float*)d_in[3];
    const float* lin1_w       = (const float*)d_in[4];
    const float* lin1_b       = (const float*)d_in[5];
    const float* lin_w        = (const float*)d_in[6];
    const float* lin_b        = (const float*)d_in[7];
    const int*   edge_index   = (const int*)d_in[8];
    const int*   target_x     = (const int*)d_in[9];
    float* out = (float*)d_out;

    unsigned*       Xp16 = (unsigned*)d_ws;                   // 25.6 MB
    unsigned*       H116 = Xp16 + PLANE2;                     // 25.6 MB
    unsigned short* Wsb  = (unsigned short*)(H116 + PLANE2);  // 32 KB
    int*            offs = (int*)(Wsb + C_CH * W_INF * DD);   // N ints
    int*            cursor = offs + N_NODES;                  // 512
    int2*           edata2 = (int2*)(cursor + 512);           // NBKT*BPAD int2 (15.2 MB)
    int2*           edataS = edata2 + (size_t)NBKT * BPAD;    // NBKT*8*QPAD int2 (16.8 MB)

    prep_kernel<<<66, 256, 0, stream>>>(Ws, Wsb, cursor);
    build_proj_kernel<<<NPART_BLK + PROJ_BLK, 256, 0, stream>>>(
        edge_index, edge_value, conv_weights, cursor, edata2, X, Wsb, Xp16);
    sortgather_kernel<<<8 * 392, 256, 0, stream>>>(cursor, edata2, edataS, offs,
                                                   Xp16, H116);
    tgt_tail_kernel<<<M_TGT / 4, 256, 0, stream>>>(H116, Xp16, offs, edataS,
                                                   conv_weights, target_x,
                                                   lin1_w, lin1_b, lin_w, lin_b, out);
}